// Round 9
// baseline (223.783 us; speedup 1.0000x reference)
//
#include <hip/hip_runtime.h>
#include <hip/hip_cooperative_groups.h>

namespace cg = cooperative_groups;

// Signed distance transform, N=192^3, exact separable EDT, packed-u16.
//   dispatch 1 (scan): wave-per-line ballot bitmask EDT along k -> u16 d^2
//   dispatch 2 (cooperative, grid = resident capacity):
//     P1: ax1 expansion tiles for B then A (grid-stride, 4608 tiles)
//     grid.sync()
//     P2: fused tiles (2304): expand A ax0 -> final A into regs -> expand B
//         ax0 in same LDS -> tanh epilogue -> write out. No A/B final writes.
//   expansion: outward min-plus on pair-rows (2 k-lines packed lo/hi u16 in
//     u32, v_pk_add/min_u16), 2 rows per wave interleaved, 4 radii/ballot,
//     exit when all d <= (r+4)^2; radii<=40 processed else exact fallback.

typedef unsigned short u16;
typedef unsigned int   u32;
typedef unsigned long long u64;
typedef u16 u16x2 __attribute__((ext_vector_type(2)));

#define NN    192
#define NN2   (192 * 192)
#define NN3   (192 * 192 * 192)

#define PAIRS 8
#define PADL  40
#define SROW  278            // words: 40 pad + 192 data + 46 pad
#define SENT16 50000
#define SENTPK 0xC350C350u

__device__ __forceinline__ u16x2 pkmin(u16x2 a, u16x2 b) { return __builtin_elementwise_min(a, b); }
__device__ __forceinline__ u16x2 pkmax(u16x2 a, u16x2 b) { return __builtin_elementwise_max(a, b); }

// ---------------------------------------------------------------------------
// Scan: wave-parallel 1D binary EDT along contiguous axis via 192-bit masks.
// ---------------------------------------------------------------------------
__device__ __forceinline__ u64 shr_pair(u64 lo, u64 hi, int s) {
    return (lo >> s) | (s ? (hi << ((64 - s) & 63)) : 0ULL);
}
__device__ __forceinline__ int dist3(u64 a0, u64 a1, u64 a2, int s) {
    u64 w0 = shr_pair(a0, a1, s);
    u64 w1 = shr_pair(a1, a2, s);
    u64 w2 = a2 >> s;
    int t0 = w0 ? __builtin_ctzll(w0) : 255;
    int t1 = w1 ? 64 + __builtin_ctzll(w1) : 255;
    int t2 = w2 ? 128 + __builtin_ctzll(w2) : 255;
    int r = t0 < t1 ? t0 : t1;
    return r < t2 ? r : t2;
}
__device__ __forceinline__ void line_edt(u64 m0, u64 m1, u64 m2, int lane,
                                         u16& o0, u16& o1, u16& o2) {
    u64 r0 = __builtin_bitreverse64(m2);
    u64 r1 = __builtin_bitreverse64(m1);
    u64 r2 = __builtin_bitreverse64(m0);
    const int s = lane, t = 63 - lane;
    int f0 = dist3(m0, m1, m2, s);
    int f1 = dist3(m1, m2, 0ULL, s);
    int f2 = dist3(m2, 0ULL, 0ULL, s);
    int b0 = dist3(r2, 0ULL, 0ULL, t);
    int b1 = dist3(r1, r2, 0ULL, t);
    int b2 = dist3(r0, r1, r2, t);
    int d0 = f0 < b0 ? f0 : b0;
    int d1 = f1 < b1 ? f1 : b1;
    int d2 = f2 < b2 ? f2 : b2;
    o0 = (d0 > 191) ? (u16)65535 : (u16)(d0 * d0);
    o1 = (d1 > 191) ? (u16)65535 : (u16)(d1 * d1);
    o2 = (d2 > 191) ? (u16)65535 : (u16)(d2 * d2);
}

__global__ __launch_bounds__(256) void sdt_scan_k(const float* __restrict__ x,
                                                  u16* __restrict__ A,
                                                  u16* __restrict__ B) {
    const int lane = threadIdx.x & 63;
    const int wid = blockIdx.x * 4 + (threadIdx.x >> 6);
    const size_t base = (size_t)wid * NN;
    float v0 = x[base + lane];
    float v1 = x[base + lane + 64];
    float v2 = x[base + lane + 128];
    u64 m0 = __ballot(v0 != 0.0f);
    u64 m1 = __ballot(v1 != 0.0f);
    u64 m2 = __ballot(v2 != 0.0f);
    u16 a0, a1, a2, b0, b1, b2;
    line_edt(~m0, ~m1, ~m2, lane, a0, a1, a2);
    line_edt(m0, m1, m2, lane, b0, b1, b2);
    A[base + lane] = a0; A[base + lane + 64] = a1; A[base + lane + 128] = a2;
    B[base + lane] = b0; B[base + lane + 64] = b1; B[base + lane + 128] = b2;
}

// ---------------------------------------------------------------------------
// Shared tile machinery. Tile = 16 k-lines = 8 packed pair-rows.
// ---------------------------------------------------------------------------
__device__ __forceinline__ void pad_init(u32* ldsw) {
    for (int idx = threadIdx.x; idx < PAIRS * 86; idx += 256) {
        int p = idx / 86, c = idx - p * 86;
        int word = (c < PADL) ? c : (c + NN);
        ldsw[p * SROW + word] = SENTPK;
    }
}

template<long ES>
__device__ __forceinline__ void stage_in(const u16* __restrict__ f, size_t base, u32* ldsw) {
    const u16x2 sentv = {(u16)SENT16, (u16)SENT16};
    for (int idx = threadIdx.x; idx < NN * 2; idx += 256) {
        int j = idx >> 1, q = idx & 1;
        uint4 v = *(const uint4*)(f + base + (size_t)j * ES + 8 * q);
        int a = PADL + j;
        ldsw[(4 * q + 0) * SROW + a] = __builtin_bit_cast(u32, pkmin(__builtin_bit_cast(u16x2, v.x), sentv));
        ldsw[(4 * q + 1) * SROW + a] = __builtin_bit_cast(u32, pkmin(__builtin_bit_cast(u16x2, v.y), sentv));
        ldsw[(4 * q + 2) * SROW + a] = __builtin_bit_cast(u32, pkmin(__builtin_bit_cast(u16x2, v.z), sentv));
        ldsw[(4 * q + 3) * SROW + a] = __builtin_bit_cast(u32, pkmin(__builtin_bit_cast(u16x2, v.w), sentv));
    }
}

template<long ES>
__device__ __forceinline__ void stage_out(u16* __restrict__ f, size_t base, const u32* ldsw) {
    for (int idx = threadIdx.x; idx < NN * 2; idx += 256) {
        int j = idx >> 1, q = idx & 1;
        int a = PADL + j;
        uint4 v;
        v.x = ldsw[(4 * q + 0) * SROW + a];
        v.y = ldsw[(4 * q + 1) * SROW + a];
        v.z = ldsw[(4 * q + 2) * SROW + a];
        v.w = ldsw[(4 * q + 3) * SROW + a];
        *(uint4*)(f + base + (size_t)j * ES + 8 * q) = v;
    }
}

__device__ __forceinline__ void full_row(const u16x2* rp, int i0, int i1, int i2,
                                         u16x2& d0, u16x2& d1, u16x2& d2) {
    const float fi0 = (float)i0, fi1 = (float)i1, fi2 = (float)i2;
    float e0l = 3e38f, e0h = 3e38f, e1l = 3e38f, e1h = 3e38f, e2l = 3e38f, e2h = 3e38f;
    for (int j = 0; j < NN; ++j) {
        u16x2 gv = rp[j];
        float gl = (float)gv.x, gh = (float)gv.y;
        float jf = (float)j;
        float t0 = jf - fi0, t1 = jf - fi1, t2 = jf - fi2;
        float s0 = t0 * t0, s1 = t1 * t1, s2 = t2 * t2;
        e0l = fminf(e0l, s0 + gl); e0h = fminf(e0h, s0 + gh);
        e1l = fminf(e1l, s1 + gl); e1h = fminf(e1h, s1 + gh);
        e2l = fminf(e2l, s2 + gl); e2h = fminf(e2h, s2 + gh);
    }
    d0.x = (u16)fminf((float)d0.x, e0l); d0.y = (u16)fminf((float)d0.y, e0h);
    d1.x = (u16)fminf((float)d1.x, e1l); d1.y = (u16)fminf((float)d1.y, e1h);
    d2.x = (u16)fminf((float)d2.x, e2l); d2.y = (u16)fminf((float)d2.y, e2h);
}

// Expansion over the whole tile: wave w owns pair-rows 2w, 2w+1 interleaved.
__device__ __forceinline__ void expand_tile(u32* ldsw) {
    const int lane = threadIdx.x & 63;
    const int w = threadIdx.x >> 6;
    const int i0 = lane, i1 = lane + 64, i2 = lane + 128;
    u16x2* pa = (u16x2*)(ldsw + (2 * w) * SROW + PADL);
    u16x2* pb = (u16x2*)(ldsw + (2 * w + 1) * SROW + PADL);
    u16x2 a0 = pa[i0], a1 = pa[i1], a2 = pa[i2];
    u16x2 b0 = pb[i0], b1 = pb[i1], b2 = pb[i2];

    int r = 1;
    bool conv = false;
    while (true) {
#pragma unroll
        for (int m = 0; m < 4; ++m) {
            u16 c = (u16)((r + m) * (r + m));
            u16x2 q = {c, c};
            a0 = pkmin(a0, pa[i0 - r - m] + q); a0 = pkmin(a0, pa[i0 + r + m] + q);
            a1 = pkmin(a1, pa[i1 - r - m] + q); a1 = pkmin(a1, pa[i1 + r + m] + q);
            a2 = pkmin(a2, pa[i2 - r - m] + q); a2 = pkmin(a2, pa[i2 + r + m] + q);
            b0 = pkmin(b0, pb[i0 - r - m] + q); b0 = pkmin(b0, pb[i0 + r + m] + q);
            b1 = pkmin(b1, pb[i1 - r - m] + q); b1 = pkmin(b1, pb[i1 + r + m] + q);
            b2 = pkmin(b2, pb[i2 - r - m] + q); b2 = pkmin(b2, pb[i2 + r + m] + q);
        }
        u16x2 mv = pkmax(pkmax(pkmax(a0, a1), pkmax(a2, b0)), pkmax(b1, b2));
        unsigned mm = (mv.x > mv.y) ? mv.x : mv.y;
        unsigned thr = (unsigned)((r + 4) * (r + 4));
        if (__all(mm <= thr)) { conv = true; break; }
        r += 4;
        if (r > 37) break;   // radii <= 40 processed
    }
    if (!conv) {
        u16x2 mv = pkmax(pkmax(pkmax(a0, a1), pkmax(a2, b0)), pkmax(b1, b2));
        unsigned mm = (mv.x > mv.y) ? mv.x : mv.y;
        if (__any(mm > 1681u)) {
            full_row(pa, i0, i1, i2, a0, a1, a2);
            full_row(pb, i0, i1, i2, b0, b1, b2);
        }
    }
    pa[i0] = a0; pa[i1] = a1; pa[i2] = a2;
    pb[i0] = b0; pb[i1] = b1; pb[i2] = b2;
}

// P1 tile: in-place ax1 pass (ES = NN).
template<long ES>
__device__ __forceinline__ void pass_tile(u16* __restrict__ f, int g, u32* ldsw) {
    const int gp = g / 12, gk = g - 12 * gp;
    const size_t base = (ES == NN ? (size_t)gp * NN2 : (size_t)gp * NN) + (size_t)gk * 16;
    __syncthreads();
    stage_in<ES>(f, base, ldsw);
    __syncthreads();
    expand_tile(ldsw);
    __syncthreads();
    stage_out<ES>(f, base, ldsw);
}

// Fused epilogue element: out = tanh((sqrt(A)-sqrt(B))/10)
__device__ __forceinline__ void emit8(float* __restrict__ out, size_t base, int idx,
                                      uint4 va, const u32* ldsw) {
    int j = idx >> 1, q = idx & 1, a = PADL + j;
    uint4 vb;
    vb.x = ldsw[(4 * q + 0) * SROW + a];
    vb.y = ldsw[(4 * q + 1) * SROW + a];
    vb.z = ldsw[(4 * q + 2) * SROW + a];
    vb.w = ldsw[(4 * q + 3) * SROW + a];
    u32 wa[4] = {va.x, va.y, va.z, va.w};
    u32 wb[4] = {vb.x, vb.y, vb.z, vb.w};
    float o[8];
#pragma unroll
    for (int s = 0; s < 4; ++s) {
        u16x2 A2 = __builtin_bit_cast(u16x2, wa[s]);
        u16x2 B2 = __builtin_bit_cast(u16x2, wb[s]);
        float x0 = (sqrtf((float)A2.x) - sqrtf((float)B2.x)) * 0.1f;
        float x1 = (sqrtf((float)A2.y) - sqrtf((float)B2.y)) * 0.1f;
        float e0 = __expf(2.f * x0);
        float e1 = __expf(2.f * x1);
        o[2 * s]     = 1.f - 2.f * __builtin_amdgcn_rcpf(e0 + 1.f);
        o[2 * s + 1] = 1.f - 2.f * __builtin_amdgcn_rcpf(e1 + 1.f);
    }
    size_t ga = base + (size_t)j * NN2 + 8 * q;
    *(float4*)(out + ga)     = *(float4*)(o);
    *(float4*)(out + ga + 4) = *(float4*)(o + 4);
}

// P2 tile: A ax0 expand -> regs; B ax0 expand in same LDS; fused tanh out.
__device__ __forceinline__ void p2_tile(const u16* __restrict__ Af,
                                        const u16* __restrict__ Bf,
                                        float* __restrict__ out,
                                        int g, u32* ldsw) {
    const int tid = threadIdx.x;
    const int gp = g / 12, gk = g - 12 * gp;
    const size_t base = (size_t)gp * NN + (size_t)gk * 16;
    __syncthreads();
    stage_in<NN2>(Af, base, ldsw);
    __syncthreads();
    expand_tile(ldsw);
    __syncthreads();
    uint4 va0 = {0, 0, 0, 0}, va1 = {0, 0, 0, 0};
    {
        int j = tid >> 1, q = tid & 1, a = PADL + j;
        va0.x = ldsw[(4 * q + 0) * SROW + a];
        va0.y = ldsw[(4 * q + 1) * SROW + a];
        va0.z = ldsw[(4 * q + 2) * SROW + a];
        va0.w = ldsw[(4 * q + 3) * SROW + a];
    }
    if (tid < 128) {
        int idx = 256 + tid;
        int j = idx >> 1, q = idx & 1, a = PADL + j;
        va1.x = ldsw[(4 * q + 0) * SROW + a];
        va1.y = ldsw[(4 * q + 1) * SROW + a];
        va1.z = ldsw[(4 * q + 2) * SROW + a];
        va1.w = ldsw[(4 * q + 3) * SROW + a];
    }
    __syncthreads();
    stage_in<NN2>(Bf, base, ldsw);
    __syncthreads();
    expand_tile(ldsw);
    __syncthreads();
    emit8(out, base, tid, va0, ldsw);
    if (tid < 128) emit8(out, base, 256 + tid, va1, ldsw);
}

// ---------------------------------------------------------------------------
// Cooperative main: P1 (4608 ax1 tiles, B first) -> grid.sync -> P2 (2304).
// ---------------------------------------------------------------------------
__global__ __launch_bounds__(256, 8) void sdt_main(u16* A, u16* B, float* out) {
    __shared__ __align__(16) u32 ldsw[PAIRS * SROW]; // 8,896 B
    pad_init(ldsw);
    for (int t = blockIdx.x; t < 4608; t += gridDim.x) {
        if (t < 2304) pass_tile<NN>(B, t, ldsw);
        else          pass_tile<NN>(A, t - 2304, ldsw);
    }
    cg::this_grid().sync();
    for (int t = blockIdx.x; t < 2304; t += gridDim.x)
        p2_tile(A, B, out, t, ldsw);
}

// Fallback path (regular launches) if cooperative launch is unavailable.
__global__ __launch_bounds__(256, 8) void sdt_p1k(u16* A, u16* B) {
    __shared__ __align__(16) u32 ldsw[PAIRS * SROW];
    pad_init(ldsw);
    int g = blockIdx.x;
    if (g < 2304) pass_tile<NN>(B, g, ldsw);
    else          pass_tile<NN>(A, g - 2304, ldsw);
}
__global__ __launch_bounds__(256, 8) void sdt_p2k(u16* A, u16* B, float* out) {
    __shared__ __align__(16) u32 ldsw[PAIRS * SROW];
    pad_init(ldsw);
    p2_tile(A, B, out, blockIdx.x, ldsw);
}

extern "C" void kernel_launch(void* const* d_in, const int* in_sizes, int n_in,
                              void* d_out, int out_size, void* d_ws, size_t ws_size,
                              hipStream_t stream) {
    const float* x = (const float*)d_in[0];
    u16* A = (u16*)d_ws;
    u16* B = (u16*)((char*)d_ws + (size_t)NN3 * 2);
    float* out = (float*)d_out;

    sdt_scan_k<<<NN2 / 4, 256, 0, stream>>>(x, A, B);

    int nb = 0;
    hipError_t qe = hipOccupancyMaxActiveBlocksPerMultiprocessor(
        &nb, (const void*)sdt_main, 256, 0);
    int grid = (qe == hipSuccess && nb > 0) ? nb * 256 : 2048;
    if (grid > 2304) grid = 2304;

    void* kargs[] = {(void*)&A, (void*)&B, (void*)&out};
    hipError_t le = hipLaunchCooperativeKernel((const void*)sdt_main,
                                               dim3(grid), dim3(256),
                                               kargs, 0, stream);
    if (le != hipSuccess) {
        sdt_p1k<<<4608, 256, 0, stream>>>(A, B);
        sdt_p2k<<<2304, 256, 0, stream>>>(A, B, out);
    }
}

// Round 10
// 104.851 us; speedup vs baseline: 2.1343x; 2.1343x over previous
//
#include <hip/hip_runtime.h>

// Signed distance transform, N=192^3, exact separable EDT, packed-u16,
// group-interleaved LDS (4 pair-rows per group -> ds_read_b128 serves 8 lines).
//   scan (axis 2): wave-per-line ballot bitmask EDT -> u16 d^2
//   expansion: outward min-plus, 4 radii per ballot, exit all d <= (r+4)^2;
//       radii <= 40 processed, else exact float full-line fallback.
//   DAG: scan -> k1{A ax1} -> k2{B ax1 | A ax0} -> k3{B ax0 + tanh out}.
// A = d^2 to nearest zero of x (ws), B = d^2 to nearest nonzero (ws+14MB).

typedef unsigned short u16;
typedef unsigned int   u32;
typedef unsigned long long u64;
typedef u16 u16x2 __attribute__((ext_vector_type(2)));

#define NN    192
#define NN2   (192 * 192)
#define NN3   (192 * 192 * 192)

#define PADL  40
#define SROW  278            // spatial positions per group (40 pad + 192 + 46)
#define SROW4 (SROW * 4)     // u32 words per group (4 interleaved pair-rows)
#define SENTPK 0xC350C350u   // 50000 | 50000<<16

__device__ __forceinline__ u32 pka32(u32 a, u32 b) {
    return __builtin_bit_cast(u32, (u16x2)(__builtin_bit_cast(u16x2, a) + __builtin_bit_cast(u16x2, b)));
}
__device__ __forceinline__ u32 pkm32(u32 a, u32 b) {
    return __builtin_bit_cast(u32, __builtin_elementwise_min(__builtin_bit_cast(u16x2, a), __builtin_bit_cast(u16x2, b)));
}
__device__ __forceinline__ u32 pkx32(u32 a, u32 b) {
    return __builtin_bit_cast(u32, __builtin_elementwise_max(__builtin_bit_cast(u16x2, a), __builtin_bit_cast(u16x2, b)));
}

// ---------------------------------------------------------------------------
// Scan: wave-parallel 1D binary EDT along contiguous axis via 192-bit masks.
// ---------------------------------------------------------------------------
__device__ __forceinline__ u64 shr_pair(u64 lo, u64 hi, int s) {
    return (lo >> s) | (s ? (hi << ((64 - s) & 63)) : 0ULL);
}
__device__ __forceinline__ int dist3(u64 a0, u64 a1, u64 a2, int s) {
    u64 w0 = shr_pair(a0, a1, s);
    u64 w1 = shr_pair(a1, a2, s);
    u64 w2 = a2 >> s;
    int t0 = w0 ? __builtin_ctzll(w0) : 255;
    int t1 = w1 ? 64 + __builtin_ctzll(w1) : 255;
    int t2 = w2 ? 128 + __builtin_ctzll(w2) : 255;
    int r = t0 < t1 ? t0 : t1;
    return r < t2 ? r : t2;
}
__device__ __forceinline__ void line_edt(u64 m0, u64 m1, u64 m2, int lane,
                                         u16& o0, u16& o1, u16& o2) {
    u64 r0 = __builtin_bitreverse64(m2);
    u64 r1 = __builtin_bitreverse64(m1);
    u64 r2 = __builtin_bitreverse64(m0);
    const int s = lane, t = 63 - lane;
    int f0 = dist3(m0, m1, m2, s);
    int f1 = dist3(m1, m2, 0ULL, s);
    int f2 = dist3(m2, 0ULL, 0ULL, s);
    int b0 = dist3(r2, 0ULL, 0ULL, t);
    int b1 = dist3(r1, r2, 0ULL, t);
    int b2 = dist3(r0, r1, r2, t);
    int d0 = f0 < b0 ? f0 : b0;
    int d1 = f1 < b1 ? f1 : b1;
    int d2 = f2 < b2 ? f2 : b2;
    o0 = (d0 > 191) ? (u16)65535 : (u16)(d0 * d0);
    o1 = (d1 > 191) ? (u16)65535 : (u16)(d1 * d1);
    o2 = (d2 > 191) ? (u16)65535 : (u16)(d2 * d2);
}

__global__ __launch_bounds__(256) void sdt_scan_k(const float* __restrict__ x,
                                                  u16* __restrict__ A,
                                                  u16* __restrict__ B) {
    const int lane = threadIdx.x & 63;
    const int wid = blockIdx.x * 4 + (threadIdx.x >> 6);
    const size_t base = (size_t)wid * NN;
    float v0 = x[base + lane];
    float v1 = x[base + lane + 64];
    float v2 = x[base + lane + 128];
    u64 m0 = __ballot(v0 != 0.0f);
    u64 m1 = __ballot(v1 != 0.0f);
    u64 m2 = __ballot(v2 != 0.0f);
    u16 a0, a1, a2, b0, b1, b2;
    line_edt(~m0, ~m1, ~m2, lane, a0, a1, a2);
    line_edt(m0, m1, m2, lane, b0, b1, b2);
    A[base + lane] = a0; A[base + lane + 64] = a1; A[base + lane + 128] = a2;
    B[base + lane] = b0; B[base + lane + 64] = b1; B[base + lane + 128] = b2;
}

// ---------------------------------------------------------------------------
// One 32-line tile pass. 4 groups x 4 interleaved pair-rows x 2 packed lines.
// ES = element stride (NN -> axis 1, NN2 -> axis 0); lines contiguous along k.
// FUSE: tanh epilogue (k3: B ax0; reads final A, writes float out).
// ---------------------------------------------------------------------------
template<long ES, bool FUSE>
__device__ __forceinline__ void pass_tile(u16* __restrict__ f, int g,
                                          const u16* __restrict__ other,
                                          float* __restrict__ outp,
                                          u32* ldsw) {
    const int tid = threadIdx.x;
    const int gp = g / 6, gk = g - 6 * gp;
    const size_t base = (ES == NN ? (size_t)gp * NN2 : (size_t)gp * NN) + (size_t)gk * 32;

    // sentinel pads: spatial [0,40) and [232,278) of each group, b128 each
    for (int idx = tid; idx < 4 * 86; idx += 256) {
        int q = idx / 86, c = idx - q * 86;
        int s = (c < PADL) ? c : (c + NN);
        uint4 sv = {SENTPK, SENTPK, SENTPK, SENTPK};
        *(uint4*)(ldsw + q * SROW4 + s * 4) = sv;
    }
    // stage in: one uint4 = 8 u16 = group q's 4 pair-rows at position j
    for (int idx = tid; idx < NN * 4; idx += 256) {
        int j = idx >> 2, q = idx & 3;
        uint4 v = *(const uint4*)(f + base + (size_t)j * ES + 8 * q);
        uint4 s;
        s.x = pkm32(v.x, SENTPK);
        s.y = pkm32(v.y, SENTPK);
        s.z = pkm32(v.z, SENTPK);
        s.w = pkm32(v.w, SENTPK);
        *(uint4*)(ldsw + q * SROW4 + (PADL + j) * 4) = s;
    }
    __syncthreads();

    const int lane = tid & 63;
    const int w = tid >> 6;
    u32* gw = ldsw + w * SROW4;
    const int c0 = PADL + lane, c1 = c0 + 64, c2 = c0 + 128;

    uint4 v0 = *(const uint4*)(gw + c0 * 4);
    uint4 v1 = *(const uint4*)(gw + c1 * 4);
    uint4 v2 = *(const uint4*)(gw + c2 * 4);
    u32 d0[4] = {v0.x, v0.y, v0.z, v0.w};
    u32 d1[4] = {v1.x, v1.y, v1.z, v1.w};
    u32 d2[4] = {v2.x, v2.y, v2.z, v2.w};

    int r = 1;
    bool conv = false;
    while (true) {
#pragma unroll
        for (int m = 0; m < 4; ++m) {
            const int rad = r + m;
            const u32 cc = (u32)(rad * rad) * 0x00010001u;
            uint4 L0 = *(const uint4*)(gw + (c0 - rad) * 4);
            uint4 R0 = *(const uint4*)(gw + (c0 + rad) * 4);
            uint4 L1 = *(const uint4*)(gw + (c1 - rad) * 4);
            uint4 R1 = *(const uint4*)(gw + (c1 + rad) * 4);
            uint4 L2 = *(const uint4*)(gw + (c2 - rad) * 4);
            uint4 R2 = *(const uint4*)(gw + (c2 + rad) * 4);
            d0[0] = pkm32(d0[0], pkm32(pka32(L0.x, cc), pka32(R0.x, cc)));
            d0[1] = pkm32(d0[1], pkm32(pka32(L0.y, cc), pka32(R0.y, cc)));
            d0[2] = pkm32(d0[2], pkm32(pka32(L0.z, cc), pka32(R0.z, cc)));
            d0[3] = pkm32(d0[3], pkm32(pka32(L0.w, cc), pka32(R0.w, cc)));
            d1[0] = pkm32(d1[0], pkm32(pka32(L1.x, cc), pka32(R1.x, cc)));
            d1[1] = pkm32(d1[1], pkm32(pka32(L1.y, cc), pka32(R1.y, cc)));
            d1[2] = pkm32(d1[2], pkm32(pka32(L1.z, cc), pka32(R1.z, cc)));
            d1[3] = pkm32(d1[3], pkm32(pka32(L1.w, cc), pka32(R1.w, cc)));
            d2[0] = pkm32(d2[0], pkm32(pka32(L2.x, cc), pka32(R2.x, cc)));
            d2[1] = pkm32(d2[1], pkm32(pka32(L2.y, cc), pka32(R2.y, cc)));
            d2[2] = pkm32(d2[2], pkm32(pka32(L2.z, cc), pka32(R2.z, cc)));
            d2[3] = pkm32(d2[3], pkm32(pka32(L2.w, cc), pka32(R2.w, cc)));
        }
        u32 mx = pkx32(pkx32(pkx32(d0[0], d0[1]), pkx32(d0[2], d0[3])),
                       pkx32(pkx32(d1[0], d1[1]), pkx32(d1[2], d1[3])));
        mx = pkx32(mx, pkx32(pkx32(d2[0], d2[1]), pkx32(d2[2], d2[3])));
        u16x2 mv = __builtin_bit_cast(u16x2, mx);
        unsigned mm = mv.x > mv.y ? mv.x : mv.y;
        unsigned thr = (unsigned)((r + 4) * (r + 4));
        if (__all(mm <= thr)) { conv = true; break; }
        r += 4;
        if (r > 37) break;   // radii <= 40 processed
    }
    if (!conv) {
        u32 mx = pkx32(pkx32(pkx32(d0[0], d0[1]), pkx32(d0[2], d0[3])),
                       pkx32(pkx32(d1[0], d1[1]), pkx32(d1[2], d1[3])));
        mx = pkx32(mx, pkx32(pkx32(d2[0], d2[1]), pkx32(d2[2], d2[3])));
        u16x2 mv = __builtin_bit_cast(u16x2, mx);
        unsigned mm = mv.x > mv.y ? mv.x : mv.y;
        if (__any(mm > 1681u)) {
            // exact full-line fallback (float domain) per pair-row
            const float fi0 = (float)lane, fi1 = (float)(lane + 64), fi2 = (float)(lane + 128);
#pragma unroll
            for (int p = 0; p < 4; ++p) {
                float e0l = 3e38f, e0h = 3e38f, e1l = 3e38f, e1h = 3e38f;
                float e2l = 3e38f, e2h = 3e38f;
                for (int j = 0; j < NN; ++j) {
                    u32 wv = gw[(PADL + j) * 4 + p];
                    float gl = (float)(wv & 0xffffu), gh = (float)(wv >> 16);
                    float jf = (float)j;
                    float t0 = jf - fi0, t1 = jf - fi1, t2 = jf - fi2;
                    float s0 = t0 * t0, s1 = t1 * t1, s2 = t2 * t2;
                    e0l = fminf(e0l, s0 + gl); e0h = fminf(e0h, s0 + gh);
                    e1l = fminf(e1l, s1 + gl); e1h = fminf(e1h, s1 + gh);
                    e2l = fminf(e2l, s2 + gl); e2h = fminf(e2h, s2 + gh);
                }
                u16x2 a;
                a = __builtin_bit_cast(u16x2, d0[p]);
                a.x = (u16)fminf((float)a.x, e0l); a.y = (u16)fminf((float)a.y, e0h);
                d0[p] = __builtin_bit_cast(u32, a);
                a = __builtin_bit_cast(u16x2, d1[p]);
                a.x = (u16)fminf((float)a.x, e1l); a.y = (u16)fminf((float)a.y, e1h);
                d1[p] = __builtin_bit_cast(u32, a);
                a = __builtin_bit_cast(u16x2, d2[p]);
                a.x = (u16)fminf((float)a.x, e2l); a.y = (u16)fminf((float)a.y, e2h);
                d2[p] = __builtin_bit_cast(u32, a);
            }
        }
    }
    // wave owns this group; all its reads completed (in-order DS per wave)
    {
        uint4 o0 = {d0[0], d0[1], d0[2], d0[3]};
        uint4 o1 = {d1[0], d1[1], d1[2], d1[3]};
        uint4 o2 = {d2[0], d2[1], d2[2], d2[3]};
        *(uint4*)(gw + c0 * 4) = o0;
        *(uint4*)(gw + c1 * 4) = o1;
        *(uint4*)(gw + c2 * 4) = o2;
    }
    __syncthreads();

    // stage out
    if (!FUSE) {
        for (int idx = tid; idx < NN * 4; idx += 256) {
            int j = idx >> 2, q = idx & 3;
            uint4 v = *(const uint4*)(ldsw + q * SROW4 + (PADL + j) * 4);
            *(uint4*)(f + base + (size_t)j * ES + 8 * q) = v;
        }
    } else {
        for (int idx = tid; idx < NN * 4; idx += 256) {
            int j = idx >> 2, q = idx & 3;
            uint4 bv = *(const uint4*)(ldsw + q * SROW4 + (PADL + j) * 4);
            size_t ga = base + (size_t)j * ES + 8 * q;
            ushort4 a0 = *(const ushort4*)(other + ga);
            ushort4 a1 = *(const ushort4*)(other + ga + 4);
            u32 wb[4] = {bv.x, bv.y, bv.z, bv.w};
            u16 wa[8] = {a0.x, a0.y, a0.z, a0.w, a1.x, a1.y, a1.z, a1.w};
            float o[8];
#pragma unroll
            for (int s = 0; s < 4; ++s) {
                u16x2 b2 = __builtin_bit_cast(u16x2, wb[s]);
                float x0 = (sqrtf((float)wa[2 * s])     - sqrtf((float)b2.x)) * 0.1f;
                float x1 = (sqrtf((float)wa[2 * s + 1]) - sqrtf((float)b2.y)) * 0.1f;
                float e0 = __expf(2.f * x0);
                float e1 = __expf(2.f * x1);
                o[2 * s]     = 1.f - 2.f * __builtin_amdgcn_rcpf(e0 + 1.f);
                o[2 * s + 1] = 1.f - 2.f * __builtin_amdgcn_rcpf(e1 + 1.f);
            }
            *(float4*)(outp + ga)     = *(float4*)(o);
            *(float4*)(outp + ga + 4) = *(float4*)(o + 4);
        }
    }
}

__global__ __launch_bounds__(256, 8) void sdt_k1(u16* __restrict__ A) {
    __shared__ __align__(16) u32 ldsw[4 * SROW4]; // 17,792 B -> 8 blocks/CU
    pass_tile<NN, false>(A, blockIdx.x, nullptr, nullptr, ldsw);
}

// k2: g<1152 -> ax1 on B (heavy, first); else ax0 on A (light, finalizes A)
__global__ __launch_bounds__(256, 8) void sdt_k2(u16* __restrict__ A, u16* __restrict__ B) {
    __shared__ __align__(16) u32 ldsw[4 * SROW4];
    int g = blockIdx.x;
    if (g < 1152) pass_tile<NN, false>(B, g, nullptr, nullptr, ldsw);
    else          pass_tile<NN2, false>(A, g - 1152, nullptr, nullptr, ldsw);
}

// k3: ax0 on B + fused tanh epilogue (reads final A, writes float out)
__global__ __launch_bounds__(256, 8) void sdt_k3(u16* __restrict__ B,
                                                 const u16* __restrict__ A,
                                                 float* __restrict__ outp) {
    __shared__ __align__(16) u32 ldsw[4 * SROW4];
    pass_tile<NN2, true>(B, blockIdx.x, A, outp, ldsw);
}

extern "C" void kernel_launch(void* const* d_in, const int* in_sizes, int n_in,
                              void* d_out, int out_size, void* d_ws, size_t ws_size,
                              hipStream_t stream) {
    const float* x = (const float*)d_in[0];
    u16* A = (u16*)d_ws;
    u16* B = (u16*)((char*)d_ws + (size_t)NN3 * 2);
    float* out = (float*)d_out;

    sdt_scan_k<<<NN2 / 4, 256, 0, stream>>>(x, A, B);
    sdt_k1<<<1152, 256, 0, stream>>>(A);
    sdt_k2<<<2304, 256, 0, stream>>>(A, B);
    sdt_k3<<<1152, 256, 0, stream>>>(B, A, out);
}

// Round 11
// 91.990 us; speedup vs baseline: 2.4327x; 1.1398x over previous
//
#include <hip/hip_runtime.h>

// Signed distance transform, N=192^3, exact separable EDT, packed-u16.
//   scan (axis 2): wave-per-line ballot bitmask EDT -> u16 d^2
//   expansion: outward min-plus on pair-rows (2 k-lines packed lo/hi u16 in
//       u32, v_pk_add/min_u16), joint 2 pair-rows per convergence loop,
//       8 radii per ballot, exit all d <= (r+8)^2; radii <= 40 processed,
//       else exact float full-line fallback.
//   DAG: scan -> p2{B ax1 (first) | A ax1} -> p3{A ax0 -> regs; B ax0; tanh}.
// A = d^2 to nearest zero of x (ws), B = d^2 to nearest nonzero (ws+14MB).

typedef unsigned short u16;
typedef unsigned int   u32;
typedef unsigned long long u64;
typedef u16 u16x2 __attribute__((ext_vector_type(2)));

#define NN    192
#define NN2   (192 * 192)
#define NN3   (192 * 192 * 192)

#define PAIRS 16
#define PADL  40
#define SROW  278            // words: 40 pad + 192 data + 46 pad
#define SENT16 50000
#define SENTPK 0xC350C350u

__device__ __forceinline__ u16x2 pkmin(u16x2 a, u16x2 b) { return __builtin_elementwise_min(a, b); }
__device__ __forceinline__ u16x2 pkmax(u16x2 a, u16x2 b) { return __builtin_elementwise_max(a, b); }

// ---------------------------------------------------------------------------
// Scan: wave-parallel 1D binary EDT along contiguous axis via 192-bit masks.
// ---------------------------------------------------------------------------
__device__ __forceinline__ u64 shr_pair(u64 lo, u64 hi, int s) {
    return (lo >> s) | (s ? (hi << ((64 - s) & 63)) : 0ULL);
}
__device__ __forceinline__ int dist3(u64 a0, u64 a1, u64 a2, int s) {
    u64 w0 = shr_pair(a0, a1, s);
    u64 w1 = shr_pair(a1, a2, s);
    u64 w2 = a2 >> s;
    int t0 = w0 ? __builtin_ctzll(w0) : 255;
    int t1 = w1 ? 64 + __builtin_ctzll(w1) : 255;
    int t2 = w2 ? 128 + __builtin_ctzll(w2) : 255;
    int r = t0 < t1 ? t0 : t1;
    return r < t2 ? r : t2;
}
__device__ __forceinline__ void line_edt(u64 m0, u64 m1, u64 m2, int lane,
                                         u16& o0, u16& o1, u16& o2) {
    u64 r0 = __builtin_bitreverse64(m2);
    u64 r1 = __builtin_bitreverse64(m1);
    u64 r2 = __builtin_bitreverse64(m0);
    const int s = lane, t = 63 - lane;
    int f0 = dist3(m0, m1, m2, s);
    int f1 = dist3(m1, m2, 0ULL, s);
    int f2 = dist3(m2, 0ULL, 0ULL, s);
    int b0 = dist3(r2, 0ULL, 0ULL, t);
    int b1 = dist3(r1, r2, 0ULL, t);
    int b2 = dist3(r0, r1, r2, t);
    int d0 = f0 < b0 ? f0 : b0;
    int d1 = f1 < b1 ? f1 : b1;
    int d2 = f2 < b2 ? f2 : b2;
    o0 = (d0 > 191) ? (u16)65535 : (u16)(d0 * d0);
    o1 = (d1 > 191) ? (u16)65535 : (u16)(d1 * d1);
    o2 = (d2 > 191) ? (u16)65535 : (u16)(d2 * d2);
}

__global__ __launch_bounds__(256) void sdt_scan_k(const float* __restrict__ x,
                                                  u16* __restrict__ A,
                                                  u16* __restrict__ B) {
    const int lane = threadIdx.x & 63;
    const int wid = blockIdx.x * 4 + (threadIdx.x >> 6);
    const size_t base = (size_t)wid * NN;
    float v0 = x[base + lane];
    float v1 = x[base + lane + 64];
    float v2 = x[base + lane + 128];
    u64 m0 = __ballot(v0 != 0.0f);
    u64 m1 = __ballot(v1 != 0.0f);
    u64 m2 = __ballot(v2 != 0.0f);
    u16 a0, a1, a2, b0, b1, b2;
    line_edt(~m0, ~m1, ~m2, lane, a0, a1, a2);
    line_edt(m0, m1, m2, lane, b0, b1, b2);
    A[base + lane] = a0; A[base + lane + 64] = a1; A[base + lane + 128] = a2;
    B[base + lane] = b0; B[base + lane + 64] = b1; B[base + lane + 128] = b2;
}

// ---------------------------------------------------------------------------
// Tile machinery: 32 k-lines = 16 packed pair-rows per block.
// ---------------------------------------------------------------------------
__device__ __forceinline__ void pad_init(u32* ldsw) {
    for (int idx = threadIdx.x; idx < PAIRS * 86; idx += 256) {
        int p = idx / 86, c = idx - p * 86;
        int word = (c < PADL) ? c : (c + NN);
        ldsw[p * SROW + word] = SENTPK;
    }
}

template<long ES>
__device__ __forceinline__ void stage_in(const u16* __restrict__ f, size_t base, u32* ldsw) {
    const u16x2 sentv = {(u16)SENT16, (u16)SENT16};
    for (int idx = threadIdx.x; idx < NN * 4; idx += 256) {
        int j = idx >> 2, q = idx & 3;
        uint4 v = *(const uint4*)(f + base + (size_t)j * ES + 8 * q);
        int a = PADL + j;
        ldsw[(4 * q + 0) * SROW + a] = __builtin_bit_cast(u32, pkmin(__builtin_bit_cast(u16x2, v.x), sentv));
        ldsw[(4 * q + 1) * SROW + a] = __builtin_bit_cast(u32, pkmin(__builtin_bit_cast(u16x2, v.y), sentv));
        ldsw[(4 * q + 2) * SROW + a] = __builtin_bit_cast(u32, pkmin(__builtin_bit_cast(u16x2, v.z), sentv));
        ldsw[(4 * q + 3) * SROW + a] = __builtin_bit_cast(u32, pkmin(__builtin_bit_cast(u16x2, v.w), sentv));
    }
}

template<long ES>
__device__ __forceinline__ void stage_out(u16* __restrict__ f, size_t base, const u32* ldsw) {
    for (int idx = threadIdx.x; idx < NN * 4; idx += 256) {
        int j = idx >> 2, q = idx & 3;
        int a = PADL + j;
        uint4 v;
        v.x = ldsw[(4 * q + 0) * SROW + a];
        v.y = ldsw[(4 * q + 1) * SROW + a];
        v.z = ldsw[(4 * q + 2) * SROW + a];
        v.w = ldsw[(4 * q + 3) * SROW + a];
        *(uint4*)(f + base + (size_t)j * ES + 8 * q) = v;
    }
}

__device__ __forceinline__ void full_row(const u16x2* rp, int i0, int i1, int i2,
                                         u16x2& d0, u16x2& d1, u16x2& d2) {
    const float fi0 = (float)i0, fi1 = (float)i1, fi2 = (float)i2;
    float e0l = 3e38f, e0h = 3e38f, e1l = 3e38f, e1h = 3e38f, e2l = 3e38f, e2h = 3e38f;
    for (int j = 0; j < NN; ++j) {
        u16x2 gv = rp[j];
        float gl = (float)gv.x, gh = (float)gv.y;
        float jf = (float)j;
        float t0 = jf - fi0, t1 = jf - fi1, t2 = jf - fi2;
        float s0 = t0 * t0, s1 = t1 * t1, s2 = t2 * t2;
        e0l = fminf(e0l, s0 + gl); e0h = fminf(e0h, s0 + gh);
        e1l = fminf(e1l, s1 + gl); e1h = fminf(e1h, s1 + gh);
        e2l = fminf(e2l, s2 + gl); e2h = fminf(e2h, s2 + gh);
    }
    d0.x = (u16)fminf((float)d0.x, e0l); d0.y = (u16)fminf((float)d0.y, e0h);
    d1.x = (u16)fminf((float)d1.x, e1l); d1.y = (u16)fminf((float)d1.y, e1h);
    d2.x = (u16)fminf((float)d2.x, e2l); d2.y = (u16)fminf((float)d2.y, e2h);
}

// Expansion: wave w owns pair-rows 4w..4w+3; TWO joint loops of 2 rows each,
// 8 radii per ballot (b32 u16x2 reads; one short serial chain per group).
__device__ __forceinline__ void expand_tile(u32* ldsw) {
    const int lane = threadIdx.x & 63;
    const int w = threadIdx.x >> 6;
    const int i0 = lane, i1 = lane + 64, i2 = lane + 128;
#pragma unroll
    for (int pg = 0; pg < 2; ++pg) {
        u16x2* ra = (u16x2*)(ldsw + (w * 4 + 2 * pg) * SROW + PADL);
        u16x2* rb = (u16x2*)(ldsw + (w * 4 + 2 * pg + 1) * SROW + PADL);
        u16x2 a0 = ra[i0], a1 = ra[i1], a2 = ra[i2];
        u16x2 b0 = rb[i0], b1 = rb[i1], b2 = rb[i2];

        int r = 1;
        bool conv = false;
        while (true) {
#pragma unroll
            for (int m = 0; m < 8; ++m) {
                const int rad = r + m;
                const u16 c = (u16)(rad * rad);
                const u16x2 q = {c, c};
                a0 = pkmin(a0, ra[i0 - rad] + q); a0 = pkmin(a0, ra[i0 + rad] + q);
                a1 = pkmin(a1, ra[i1 - rad] + q); a1 = pkmin(a1, ra[i1 + rad] + q);
                a2 = pkmin(a2, ra[i2 - rad] + q); a2 = pkmin(a2, ra[i2 + rad] + q);
                b0 = pkmin(b0, rb[i0 - rad] + q); b0 = pkmin(b0, rb[i0 + rad] + q);
                b1 = pkmin(b1, rb[i1 - rad] + q); b1 = pkmin(b1, rb[i1 + rad] + q);
                b2 = pkmin(b2, rb[i2 - rad] + q); b2 = pkmin(b2, rb[i2 + rad] + q);
            }
            u16x2 mv = pkmax(pkmax(pkmax(a0, a1), pkmax(a2, b0)), pkmax(b1, b2));
            unsigned mm = (mv.x > mv.y) ? mv.x : mv.y;
            unsigned thr = (unsigned)((r + 8) * (r + 8));
            if (__all(mm <= thr)) { conv = true; break; }
            r += 8;
            if (r > 33) break;   // radii <= 40 processed
        }
        if (!conv) {
            u16x2 mv = pkmax(pkmax(pkmax(a0, a1), pkmax(a2, b0)), pkmax(b1, b2));
            unsigned mm = (mv.x > mv.y) ? mv.x : mv.y;
            if (__any(mm > 1681u)) {
                full_row(ra, i0, i1, i2, a0, a1, a2);
                full_row(rb, i0, i1, i2, b0, b1, b2);
            }
        }
        // wave owns these rows; its reads completed (in-order DS per wave)
        ra[i0] = a0; ra[i1] = a1; ra[i2] = a2;
        rb[i0] = b0; rb[i1] = b1; rb[i2] = b2;
    }
}

// ---------------------------------------------------------------------------
// p2: in-place ax1 pass; g<1152 -> B tile (heavy, first), else A tile.
// ---------------------------------------------------------------------------
__global__ __launch_bounds__(256, 8) void sdt_p2(u16* __restrict__ A, u16* __restrict__ B) {
    __shared__ __align__(16) u32 ldsw[PAIRS * SROW]; // 17,792 B -> 8 blocks/CU
    int g = blockIdx.x;
    u16* f = (g < 1152) ? B : A;
    int t = (g < 1152) ? g : g - 1152;
    const int gp = t / 6, gk = t - 6 * gp;
    const size_t base = (size_t)gp * NN2 + (size_t)gk * 32;
    pad_init(ldsw);
    stage_in<NN>(f, base, ldsw);
    __syncthreads();
    expand_tile(ldsw);
    __syncthreads();
    stage_out<NN>(f, base, ldsw);
}

// ---------------------------------------------------------------------------
// p3: fused final pass. Per 32-k-line slab: expand A ax0 -> keep in regs;
// expand B ax0 in same LDS; tanh epilogue writes float out. No field writes.
// ---------------------------------------------------------------------------
__global__ __launch_bounds__(256, 8) void sdt_p3f(u16* __restrict__ B,
                                                  const u16* __restrict__ A,
                                                  float* __restrict__ out) {
    __shared__ __align__(16) u32 ldsw[PAIRS * SROW];
    const int tid = threadIdx.x;
    const int g = blockIdx.x;
    const int gp = g / 6, gk = g - 6 * gp;
    const size_t base = (size_t)gp * NN + (size_t)gk * 32;

    pad_init(ldsw);
    stage_in<NN2>(A, base, ldsw);
    __syncthreads();
    expand_tile(ldsw);
    __syncthreads();
    uint4 va[3];
#pragma unroll
    for (int t = 0; t < 3; ++t) {
        int idx = tid + 256 * t;
        int j = idx >> 2, q = idx & 3, a = PADL + j;
        va[t].x = ldsw[(4 * q + 0) * SROW + a];
        va[t].y = ldsw[(4 * q + 1) * SROW + a];
        va[t].z = ldsw[(4 * q + 2) * SROW + a];
        va[t].w = ldsw[(4 * q + 3) * SROW + a];
    }
    __syncthreads();
    stage_in<NN2>(B, base, ldsw);
    __syncthreads();
    expand_tile(ldsw);
    __syncthreads();
#pragma unroll
    for (int t = 0; t < 3; ++t) {
        int idx = tid + 256 * t;
        int j = idx >> 2, q = idx & 3, a = PADL + j;
        uint4 vb;
        vb.x = ldsw[(4 * q + 0) * SROW + a];
        vb.y = ldsw[(4 * q + 1) * SROW + a];
        vb.z = ldsw[(4 * q + 2) * SROW + a];
        vb.w = ldsw[(4 * q + 3) * SROW + a];
        u32 wa[4] = {va[t].x, va[t].y, va[t].z, va[t].w};
        u32 wb[4] = {vb.x, vb.y, vb.z, vb.w};
        float o[8];
#pragma unroll
        for (int s = 0; s < 4; ++s) {
            u16x2 A2 = __builtin_bit_cast(u16x2, wa[s]);
            u16x2 B2 = __builtin_bit_cast(u16x2, wb[s]);
            float x0 = (sqrtf((float)A2.x) - sqrtf((float)B2.x)) * 0.1f;
            float x1 = (sqrtf((float)A2.y) - sqrtf((float)B2.y)) * 0.1f;
            float e0 = __expf(2.f * x0);
            float e1 = __expf(2.f * x1);
            o[2 * s]     = 1.f - 2.f * __builtin_amdgcn_rcpf(e0 + 1.f);
            o[2 * s + 1] = 1.f - 2.f * __builtin_amdgcn_rcpf(e1 + 1.f);
        }
        size_t ga = base + (size_t)j * NN2 + 8 * q;
        *(float4*)(out + ga)     = *(float4*)(o);
        *(float4*)(out + ga + 4) = *(float4*)(o + 4);
    }
}

extern "C" void kernel_launch(void* const* d_in, const int* in_sizes, int n_in,
                              void* d_out, int out_size, void* d_ws, size_t ws_size,
                              hipStream_t stream) {
    const float* x = (const float*)d_in[0];
    u16* A = (u16*)d_ws;
    u16* B = (u16*)((char*)d_ws + (size_t)NN3 * 2);
    float* out = (float*)d_out;

    sdt_scan_k<<<NN2 / 4, 256, 0, stream>>>(x, A, B);
    sdt_p2<<<2304, 256, 0, stream>>>(A, B);
    sdt_p3f<<<1152, 256, 0, stream>>>(B, A, out);
}

// Round 12
// 85.011 us; speedup vs baseline: 2.6324x; 1.0821x over previous
//
#include <hip/hip_runtime.h>

// Signed distance transform, N=192^3, exact separable EDT, packed-u16.
//   scan (axis 2): wave-per-line ballot bitmask EDT -> u16 d^2
//   expansion: outward min-plus on pair-rows (2 k-lines packed lo/hi u16 in
//       u32, v_pk_add/min_u16), PER-ROW convergence loops (measured best),
//       8 radii per ballot, exit all d <= (r+8)^2; radii <= 40 processed,
//       else exact float full-line fallback.
//   Tile = 16 k-lines = 8 pair-rows -> 2 serial row-chains per wave (latency).
//   DAG: scan -> p2{B ax1 (first) | A ax1} -> p3{A ax0 -> regs; B ax0; tanh}.
// A = d^2 to nearest zero of x (ws), B = d^2 to nearest nonzero (ws+14MB).

typedef unsigned short u16;
typedef unsigned int   u32;
typedef unsigned long long u64;
typedef u16 u16x2 __attribute__((ext_vector_type(2)));

#define NN    192
#define NN2   (192 * 192)
#define NN3   (192 * 192 * 192)

#define PAIRS 8
#define PADL  40
#define SROW  278            // words: 40 pad + 192 data + 46 pad
#define SENT16 50000
#define SENTPK 0xC350C350u

__device__ __forceinline__ u16x2 pkmin(u16x2 a, u16x2 b) { return __builtin_elementwise_min(a, b); }
__device__ __forceinline__ u16x2 pkmax(u16x2 a, u16x2 b) { return __builtin_elementwise_max(a, b); }

// ---------------------------------------------------------------------------
// Scan: wave-parallel 1D binary EDT along contiguous axis via 192-bit masks.
// ---------------------------------------------------------------------------
__device__ __forceinline__ u64 shr_pair(u64 lo, u64 hi, int s) {
    return (lo >> s) | (s ? (hi << ((64 - s) & 63)) : 0ULL);
}
__device__ __forceinline__ int dist3(u64 a0, u64 a1, u64 a2, int s) {
    u64 w0 = shr_pair(a0, a1, s);
    u64 w1 = shr_pair(a1, a2, s);
    u64 w2 = a2 >> s;
    int t0 = w0 ? __builtin_ctzll(w0) : 255;
    int t1 = w1 ? 64 + __builtin_ctzll(w1) : 255;
    int t2 = w2 ? 128 + __builtin_ctzll(w2) : 255;
    int r = t0 < t1 ? t0 : t1;
    return r < t2 ? r : t2;
}
__device__ __forceinline__ void line_edt(u64 m0, u64 m1, u64 m2, int lane,
                                         u16& o0, u16& o1, u16& o2) {
    u64 r0 = __builtin_bitreverse64(m2);
    u64 r1 = __builtin_bitreverse64(m1);
    u64 r2 = __builtin_bitreverse64(m0);
    const int s = lane, t = 63 - lane;
    int f0 = dist3(m0, m1, m2, s);
    int f1 = dist3(m1, m2, 0ULL, s);
    int f2 = dist3(m2, 0ULL, 0ULL, s);
    int b0 = dist3(r2, 0ULL, 0ULL, t);
    int b1 = dist3(r1, r2, 0ULL, t);
    int b2 = dist3(r0, r1, r2, t);
    int d0 = f0 < b0 ? f0 : b0;
    int d1 = f1 < b1 ? f1 : b1;
    int d2 = f2 < b2 ? f2 : b2;
    o0 = (d0 > 191) ? (u16)65535 : (u16)(d0 * d0);
    o1 = (d1 > 191) ? (u16)65535 : (u16)(d1 * d1);
    o2 = (d2 > 191) ? (u16)65535 : (u16)(d2 * d2);
}

__global__ __launch_bounds__(256) void sdt_scan_k(const float* __restrict__ x,
                                                  u16* __restrict__ A,
                                                  u16* __restrict__ B) {
    const int lane = threadIdx.x & 63;
    const int wid = blockIdx.x * 4 + (threadIdx.x >> 6);
    const size_t base = (size_t)wid * NN;
    float v0 = x[base + lane];
    float v1 = x[base + lane + 64];
    float v2 = x[base + lane + 128];
    u64 m0 = __ballot(v0 != 0.0f);
    u64 m1 = __ballot(v1 != 0.0f);
    u64 m2 = __ballot(v2 != 0.0f);
    u16 a0, a1, a2, b0, b1, b2;
    line_edt(~m0, ~m1, ~m2, lane, a0, a1, a2);
    line_edt(m0, m1, m2, lane, b0, b1, b2);
    A[base + lane] = a0; A[base + lane + 64] = a1; A[base + lane + 128] = a2;
    B[base + lane] = b0; B[base + lane + 64] = b1; B[base + lane + 128] = b2;
}

// ---------------------------------------------------------------------------
// Tile machinery: 16 k-lines = 8 packed pair-rows per block.
// ---------------------------------------------------------------------------
__device__ __forceinline__ void pad_init(u32* ldsw) {
    for (int idx = threadIdx.x; idx < PAIRS * 86; idx += 256) {
        int p = idx / 86, c = idx - p * 86;
        int word = (c < PADL) ? c : (c + NN);
        ldsw[p * SROW + word] = SENTPK;
    }
}

template<long ES>
__device__ __forceinline__ void stage_in(const u16* __restrict__ f, size_t base, u32* ldsw) {
    const u16x2 sentv = {(u16)SENT16, (u16)SENT16};
    for (int idx = threadIdx.x; idx < NN * 2; idx += 256) {
        int j = idx >> 1, q = idx & 1;
        uint4 v = *(const uint4*)(f + base + (size_t)j * ES + 8 * q);
        int a = PADL + j;
        ldsw[(4 * q + 0) * SROW + a] = __builtin_bit_cast(u32, pkmin(__builtin_bit_cast(u16x2, v.x), sentv));
        ldsw[(4 * q + 1) * SROW + a] = __builtin_bit_cast(u32, pkmin(__builtin_bit_cast(u16x2, v.y), sentv));
        ldsw[(4 * q + 2) * SROW + a] = __builtin_bit_cast(u32, pkmin(__builtin_bit_cast(u16x2, v.z), sentv));
        ldsw[(4 * q + 3) * SROW + a] = __builtin_bit_cast(u32, pkmin(__builtin_bit_cast(u16x2, v.w), sentv));
    }
}

template<long ES>
__device__ __forceinline__ void stage_out(u16* __restrict__ f, size_t base, const u32* ldsw) {
    for (int idx = threadIdx.x; idx < NN * 2; idx += 256) {
        int j = idx >> 1, q = idx & 1;
        int a = PADL + j;
        uint4 v;
        v.x = ldsw[(4 * q + 0) * SROW + a];
        v.y = ldsw[(4 * q + 1) * SROW + a];
        v.z = ldsw[(4 * q + 2) * SROW + a];
        v.w = ldsw[(4 * q + 3) * SROW + a];
        *(uint4*)(f + base + (size_t)j * ES + 8 * q) = v;
    }
}

__device__ __forceinline__ void full_row(const u16x2* rp, int i0, int i1, int i2,
                                         u16x2& d0, u16x2& d1, u16x2& d2) {
    const float fi0 = (float)i0, fi1 = (float)i1, fi2 = (float)i2;
    float e0l = 3e38f, e0h = 3e38f, e1l = 3e38f, e1h = 3e38f, e2l = 3e38f, e2h = 3e38f;
    for (int j = 0; j < NN; ++j) {
        u16x2 gv = rp[j];
        float gl = (float)gv.x, gh = (float)gv.y;
        float jf = (float)j;
        float t0 = jf - fi0, t1 = jf - fi1, t2 = jf - fi2;
        float s0 = t0 * t0, s1 = t1 * t1, s2 = t2 * t2;
        e0l = fminf(e0l, s0 + gl); e0h = fminf(e0h, s0 + gh);
        e1l = fminf(e1l, s1 + gl); e1h = fminf(e1h, s1 + gh);
        e2l = fminf(e2l, s2 + gl); e2h = fminf(e2h, s2 + gh);
    }
    d0.x = (u16)fminf((float)d0.x, e0l); d0.y = (u16)fminf((float)d0.y, e0h);
    d1.x = (u16)fminf((float)d1.x, e1l); d1.y = (u16)fminf((float)d1.y, e1h);
    d2.x = (u16)fminf((float)d2.x, e2l); d2.y = (u16)fminf((float)d2.y, e2h);
}

// Expansion: wave w owns pair-rows 2w, 2w+1; independent per-row loops
// (measured best structure), 8 radii per ballot, b32 u16x2 reads.
__device__ __forceinline__ void expand_tile(u32* ldsw) {
    const int lane = threadIdx.x & 63;
    const int w = threadIdx.x >> 6;
    const int i0 = lane, i1 = lane + 64, i2 = lane + 128;
#pragma unroll
    for (int pp = 0; pp < 2; ++pp) {
        u16x2* rp = (u16x2*)(ldsw + (2 * w + pp) * SROW + PADL);
        u16x2 d0 = rp[i0], d1 = rp[i1], d2 = rp[i2];

        int r = 1;
        bool conv = false;
        while (true) {
#pragma unroll
            for (int m = 0; m < 8; ++m) {
                const int rad = r + m;
                const u16 c = (u16)(rad * rad);
                const u16x2 q = {c, c};
                d0 = pkmin(d0, rp[i0 - rad] + q); d0 = pkmin(d0, rp[i0 + rad] + q);
                d1 = pkmin(d1, rp[i1 - rad] + q); d1 = pkmin(d1, rp[i1 + rad] + q);
                d2 = pkmin(d2, rp[i2 - rad] + q); d2 = pkmin(d2, rp[i2 + rad] + q);
            }
            u16x2 mv = pkmax(pkmax(d0, d1), d2);
            unsigned mm = (mv.x > mv.y) ? mv.x : mv.y;
            unsigned thr = (unsigned)((r + 8) * (r + 8));
            if (__all(mm <= thr)) { conv = true; break; }
            r += 8;
            if (r > 33) break;   // radii <= 40 processed
        }
        if (!conv) {
            u16x2 mv = pkmax(pkmax(d0, d1), d2);
            unsigned mm = (mv.x > mv.y) ? mv.x : mv.y;
            if (__any(mm > 1681u)) {
                full_row(rp, i0, i1, i2, d0, d1, d2);
            }
        }
        // wave owns this row; its reads completed (in-order DS per wave)
        rp[i0] = d0; rp[i1] = d1; rp[i2] = d2;
    }
}

// ---------------------------------------------------------------------------
// p2: in-place ax1 pass; g<2304 -> B tile (heavy, first), else A tile.
// Tile t: plane gp = t/12, k-chunk gk = t%12 (16 lines).
// ---------------------------------------------------------------------------
__global__ __launch_bounds__(256, 8) void sdt_p2(u16* __restrict__ A, u16* __restrict__ B) {
    __shared__ __align__(16) u32 ldsw[PAIRS * SROW]; // 8,896 B
    int g = blockIdx.x;
    u16* f = (g < 2304) ? B : A;
    int t = (g < 2304) ? g : g - 2304;
    const int gp = t / 12, gk = t - 12 * gp;
    const size_t base = (size_t)gp * NN2 + (size_t)gk * 16;
    pad_init(ldsw);
    stage_in<NN>(f, base, ldsw);
    __syncthreads();
    expand_tile(ldsw);
    __syncthreads();
    stage_out<NN>(f, base, ldsw);
}

// ---------------------------------------------------------------------------
// p3: fused final pass per 16-k-line slab: expand A ax0 -> regs; expand B ax0
// in same LDS; tanh epilogue writes float out. No field writes.
// ---------------------------------------------------------------------------
__global__ __launch_bounds__(256, 8) void sdt_p3f(u16* __restrict__ B,
                                                  const u16* __restrict__ A,
                                                  float* __restrict__ out) {
    __shared__ __align__(16) u32 ldsw[PAIRS * SROW];
    const int tid = threadIdx.x;
    const int g = blockIdx.x;
    const int gp = g / 12, gk = g - 12 * gp;
    const size_t base = (size_t)gp * NN + (size_t)gk * 16;

    pad_init(ldsw);
    stage_in<NN2>(A, base, ldsw);
    __syncthreads();
    expand_tile(ldsw);
    __syncthreads();
    uint4 va0, va1 = {0, 0, 0, 0};
    {
        int j = tid >> 1, q = tid & 1, a = PADL + j;
        va0.x = ldsw[(4 * q + 0) * SROW + a];
        va0.y = ldsw[(4 * q + 1) * SROW + a];
        va0.z = ldsw[(4 * q + 2) * SROW + a];
        va0.w = ldsw[(4 * q + 3) * SROW + a];
    }
    if (tid < 128) {
        int idx = 256 + tid;
        int j = idx >> 1, q = idx & 1, a = PADL + j;
        va1.x = ldsw[(4 * q + 0) * SROW + a];
        va1.y = ldsw[(4 * q + 1) * SROW + a];
        va1.z = ldsw[(4 * q + 2) * SROW + a];
        va1.w = ldsw[(4 * q + 3) * SROW + a];
    }
    __syncthreads();
    stage_in<NN2>(B, base, ldsw);
    __syncthreads();
    expand_tile(ldsw);
    __syncthreads();
#pragma unroll
    for (int t = 0; t < 2; ++t) {
        if (t == 1 && tid >= 128) break;
        int idx = tid + 256 * t;
        int j = idx >> 1, q = idx & 1, a = PADL + j;
        uint4 va = (t == 0) ? va0 : va1;
        uint4 vb;
        vb.x = ldsw[(4 * q + 0) * SROW + a];
        vb.y = ldsw[(4 * q + 1) * SROW + a];
        vb.z = ldsw[(4 * q + 2) * SROW + a];
        vb.w = ldsw[(4 * q + 3) * SROW + a];
        u32 wa[4] = {va.x, va.y, va.z, va.w};
        u32 wb[4] = {vb.x, vb.y, vb.z, vb.w};
        float o[8];
#pragma unroll
        for (int s = 0; s < 4; ++s) {
            u16x2 A2 = __builtin_bit_cast(u16x2, wa[s]);
            u16x2 B2 = __builtin_bit_cast(u16x2, wb[s]);
            float x0 = (sqrtf((float)A2.x) - sqrtf((float)B2.x)) * 0.1f;
            float x1 = (sqrtf((float)A2.y) - sqrtf((float)B2.y)) * 0.1f;
            float e0 = __expf(2.f * x0);
            float e1 = __expf(2.f * x1);
            o[2 * s]     = 1.f - 2.f * __builtin_amdgcn_rcpf(e0 + 1.f);
            o[2 * s + 1] = 1.f - 2.f * __builtin_amdgcn_rcpf(e1 + 1.f);
        }
        size_t ga = base + (size_t)j * NN2 + 8 * q;
        *(float4*)(out + ga)     = *(float4*)(o);
        *(float4*)(out + ga + 4) = *(float4*)(o + 4);
    }
}

extern "C" void kernel_launch(void* const* d_in, const int* in_sizes, int n_in,
                              void* d_out, int out_size, void* d_ws, size_t ws_size,
                              hipStream_t stream) {
    const float* x = (const float*)d_in[0];
    u16* A = (u16*)d_ws;
    u16* B = (u16*)((char*)d_ws + (size_t)NN3 * 2);
    float* out = (float*)d_out;

    sdt_scan_k<<<NN2 / 4, 256, 0, stream>>>(x, A, B);
    sdt_p2<<<4608, 256, 0, stream>>>(A, B);
    sdt_p3f<<<2304, 256, 0, stream>>>(B, A, out);
}